// Round 14
// baseline (958.052 us; speedup 1.0000x reference)
//
#include <hip/hip_runtime.h>

#define N_NODES 1000
#define BATCH 16
#define SEQ 12
#define IN_DIM 3
#define HDIM 64
#define E_EDGES 16000
#define EN (E_EDGES + N_NODES)
#define NB (N_NODES * BATCH)

typedef unsigned int u32;
typedef unsigned short u16;
typedef __fp16 h2_t __attribute__((ext_vector_type(2)));

__device__ __forceinline__ float sigmoidf(float x) { return 1.0f / (1.0f + expf(-x)); }

__device__ __forceinline__ u16 f2bf(float x) {
    u32 u = __builtin_bit_cast(u32, x);
    u32 r = (u + 0x7fffu + ((u >> 16) & 1u)) >> 16;
    return (u16)r;
}
__device__ __forceinline__ float bf2f(u32 h) {
    return __builtin_bit_cast(float, (h & 0xffffu) << 16);
}
__device__ __forceinline__ u32 pack2(float a, float b) {
    return (u32)f2bf(a) | ((u32)f2bf(b) << 16);
}

// f16 pair pack / dot2 helpers
__device__ __forceinline__ u32 pkh2(float a, float b) {
    h2_t h = __builtin_amdgcn_cvt_pkrtz(a, b);
    return __builtin_bit_cast(u32, h);
}
#if __has_builtin(__builtin_amdgcn_fdot2)
__device__ __forceinline__ float dot2(u32 a, u32 b, float c) {
    return __builtin_amdgcn_fdot2(__builtin_bit_cast(h2_t, a),
                                  __builtin_bit_cast(h2_t, b), c, false);
}
#else
__device__ __forceinline__ float dot2(u32 a, u32 b, float c) {
    h2_t x = __builtin_bit_cast(h2_t, a);
    h2_t y = __builtin_bit_cast(h2_t, b);
    return c + (float)x.x * (float)y.x + (float)x.y * (float)y.y;
}
#endif

// ---------------------------------------------------------------------------
// prep: copy carries, f16 k-paired weight packs, Wi1T, fpred, zero prev
// ---------------------------------------------------------------------------
__global__ void prep_kernel(const float* __restrict__ hidden0,
                            const float* __restrict__ hidden1,
                            const float* __restrict__ features,
                            const float* __restrict__ W3,
                            const float* __restrict__ b3,
                            const float* __restrict__ Wo,
                            const float* __restrict__ bo,
                            const float* __restrict__ Wh1,
                            const float* __restrict__ Wi1,
                            const float* __restrict__ Wi2,
                            const float* __restrict__ Wh2,
                            float* __restrict__ h0, float* __restrict__ h1,
                            u32* __restrict__ WhH2,
                            u32* __restrict__ MH2,
                            u32* __restrict__ W2H2,
                            float* __restrict__ Wi1T,
                            float* __restrict__ fpred, float* __restrict__ prev)
{
    int tid = blockIdx.x * blockDim.x + threadIdx.x;
    int stride = gridDim.x * blockDim.x;

    for (int i = tid; i < NB * HDIM; i += stride) { h0[i] = hidden0[i]; h1[i] = hidden1[i]; }

    for (int i = tid; i < 32 * 192; i += stride) {
        int k2 = i / 192, gj = i % 192;
        WhH2[i] = pkh2(Wh1[gj * 64 + 2 * k2], Wh1[gj * 64 + 2 * k2 + 1]);
    }

    for (int i = tid; i < 32 * 384; i += stride) {
        int k2 = i / 384, c = i % 384;
        int grp = c / 64, h = c % 64;
        float v0, v1;
        {
            int k = 2 * k2;
            int kk = (grp < 3 ? k : 64 + k) * 64 + h;
            v0 = (grp == 0 || grp == 3) ? W3[kk * 2]
               : (grp == 1 || grp == 4) ? W3[kk * 2 + 1] : b3[kk];
        }
        {
            int k = 2 * k2 + 1;
            int kk = (grp < 3 ? k : 64 + k) * 64 + h;
            v1 = (grp == 0 || grp == 3) ? W3[kk * 2]
               : (grp == 1 || grp == 4) ? W3[kk * 2 + 1] : b3[kk];
        }
        MH2[i] = pkh2(v0, v1);
    }

    for (int i = tid; i < 32 * 384; i += stride) {
        int k2 = i / 384, cc = i % 384;
        float v0, v1;
        if (cc < 192) {
            v0 = Wi2[cc * 64 + 2 * k2]; v1 = Wi2[cc * 64 + 2 * k2 + 1];
        } else {
            int gj = cc - 192;
            v0 = Wh2[gj * 64 + 2 * k2]; v1 = Wh2[gj * 64 + 2 * k2 + 1];
        }
        W2H2[i] = pkh2(v0, v1);
    }

    for (int i = tid; i < 3 * 192; i += stride) {
        int c = i / 192, gj = i % 192;
        Wi1T[i] = Wi1[gj * 3 + c];
    }

    for (int i = tid; i < NB; i += stride) prev[i] = 0.0f;

    for (int n = tid; n < N_NODES; n += stride) {
        float acc = bo[0];
        for (int h = 0; h < HDIM; ++h) acc += features[n * HDIM + h] * Wo[64 + h];
        fpred[n] = acc;
    }
}

// ---------------------------------------------------------------------------
// CSR build (runs once per launch)
// ---------------------------------------------------------------------------
__global__ void deg_init_kernel(int* __restrict__ deg)
{
    int n = blockIdx.x * blockDim.x + threadIdx.x;
    if (n < N_NODES) deg[n] = 1;   // self-loop
}

__global__ void deg_count_kernel(const int* __restrict__ edge_index, int* __restrict__ deg)
{
    int e = blockIdx.x * blockDim.x + threadIdx.x;
    if (e < E_EDGES) atomicAdd(&deg[edge_index[E_EDGES + e]], 1);
}

__global__ __launch_bounds__(1024) void scan_kernel(const int* __restrict__ deg,
                                                    int* __restrict__ row_ptr,
                                                    int* __restrict__ row_fill)
{
    __shared__ int s[1024];
    int tid = threadIdx.x;
    int x = (tid < N_NODES) ? deg[tid] : 0;
    s[tid] = x;
    __syncthreads();
    for (int off = 1; off < 1024; off <<= 1) {
        int v = (tid >= off) ? s[tid - off] : 0;
        __syncthreads();
        s[tid] += v;
        __syncthreads();
    }
    int incl = s[tid];
    int excl = incl - x;
    if (tid < N_NODES) { row_ptr[tid] = excl; row_fill[tid] = excl; }
    if (tid == N_NODES - 1) row_ptr[N_NODES] = incl;
}

__global__ void scatter_kernel(const int* __restrict__ edge_index,
                               int* __restrict__ row_fill,
                               int* __restrict__ csr_src,
                               int* __restrict__ perm)
{
    int e = blockIdx.x * blockDim.x + threadIdx.x;
    if (e < E_EDGES) {
        int s = edge_index[e];
        int d = edge_index[E_EDGES + e];
        int p = atomicAdd(&row_fill[d], 1);
        csr_src[p] = s;
        perm[e] = p;
    } else if (e < EN) {
        int n = e - E_EDGES;
        int p = atomicAdd(&row_fill[n], 1);
        csr_src[p] = n;
        perm[e] = p;
    }
}

// ---------------------------------------------------------------------------
// edge MLP -> u,v written in CSR order via perm (runs once)
// ---------------------------------------------------------------------------
__global__ __launch_bounds__(256) void edge_mlp_kernel(const int* __restrict__ edge_index,
                                                       const float* __restrict__ features,
                                                       const float* __restrict__ W1,
                                                       const float* __restrict__ b1,
                                                       const float* __restrict__ W2,
                                                       const float* __restrict__ b2,
                                                       const int* __restrict__ perm,
                                                       float* __restrict__ csr_uv)
{
    int w = threadIdx.x >> 6, j = threadIdx.x & 63;
    int e = blockIdx.x * 4 + w;
    int s, d;
    if (e < E_EDGES) { s = edge_index[e]; d = edge_index[E_EDGES + e]; }
    else             { s = e - E_EDGES; d = s; }

    __shared__ float ft[4][128];
    __shared__ float w1s[4][16];
    ft[w][j]      = features[d * HDIM + j];   // dst half first
    ft[w][64 + j] = features[s * HDIM + j];
    __syncthreads();

    int o = j & 15, part = j >> 4;
    float acc = 0.0f;
    #pragma unroll 8
    for (int kk = 0; kk < 32; ++kk)
        acc += ft[w][part * 32 + kk] * W1[o * 128 + part * 32 + kk];
    acc += __shfl_xor(acc, 16, 64);
    acc += __shfl_xor(acc, 32, 64);
    if (j < 16) w1s[w][j] = sigmoidf(acc + b1[j]);
    __syncthreads();
    if (j < 2) {
        float a2 = b2[j];
        #pragma unroll
        for (int k = 0; k < 16; ++k) a2 += w1s[w][k] * W2[j * 16 + k];
        csr_uv[perm[e] * 2 + j] = sigmoidf(a2);
    }
}

// ---------------------------------------------------------------------------
// Fused GRU1 + projection, fdot2 inner loops. 256 threads = 4 waves x 8 rows.
// hs fp32 (hj, repack source) + hp f16-pair LDS; no register staging arrays.
// ---------------------------------------------------------------------------
__global__ __launch_bounds__(256) void gru1_proj_kernel(const float* __restrict__ labels,
                                                        const float* __restrict__ prev,
                                                        const float* __restrict__ Wi1T,
                                                        const u32* __restrict__ WhH2,
                                                        const float* __restrict__ bi1,
                                                        const float* __restrict__ bh1,
                                                        const u32* __restrict__ MH2,
                                                        float* __restrict__ h0,
                                                        uint2* __restrict__ Pd,
                                                        u32* __restrict__ PsF8,
                                                        int t)
{
    int w = threadIdx.x >> 6, j = threadIdx.x & 63;
    int rbase = blockIdx.x * 32 + w * 8;
    __shared__ float hs[32][64];   // fp32 state (8 KB)
    __shared__ u32 hp[32][32];     // f16-pair state (4 KB)

    #pragma unroll
    for (int rr = 0; rr < 8; ++rr)
        hs[w * 8 + rr][j] = h0[(size_t)(rbase + rr) * HDIM + j];

    // wave-local repack: 8 rows x 32 pairs = 256 entries, 4 per lane
    #pragma unroll
    for (int q = 0; q < 4; ++q) {
        int idx = q * 64 + j;
        int r = idx >> 5, k2 = idx & 31;
        float2 v = *(const float2*)&hs[w * 8 + r][k2 * 2];
        hp[w * 8 + r][k2] = pkh2(v.x, v.y);
    }

    // ---- gate: ar/az/an via dot2 ----
    float ar[8], az[8], an[8];
    {
        float br = bh1[j], bz = bh1[64 + j], bn = bh1[128 + j];
        #pragma unroll
        for (int rr = 0; rr < 8; ++rr) { ar[rr] = br; az[rr] = bz; an[rr] = bn; }
    }

    for (int k2 = 0; k2 < 32; ++k2) {
        u32 wr = WhH2[k2 * 192 + j];
        u32 wz = WhH2[k2 * 192 + 64 + j];
        u32 wn = WhH2[k2 * 192 + 128 + j];
        #pragma unroll
        for (int rr = 0; rr < 8; ++rr) {
            u32 hh = hp[w * 8 + rr][k2];
            ar[rr] = dot2(wr, hh, ar[rr]);
            az[rr] = dot2(wz, hh, az[rr]);
            an[rr] = dot2(wn, hh, an[rr]);
        }
    }

    float wi00 = Wi1T[j],       wi01 = Wi1T[64 + j],       wi02 = Wi1T[128 + j];
    float wi10 = Wi1T[192 + j], wi11 = Wi1T[192 + 64 + j], wi12 = Wi1T[192 + 128 + j];
    float wi20 = Wi1T[384 + j], wi21 = Wi1T[384 + 64 + j], wi22 = Wi1T[384 + 128 + j];
    float bir = bi1[j], biz = bi1[64 + j], bin_ = bi1[128 + j];

    #pragma unroll
    for (int rr = 0; rr < 8; ++rr) {
        int row = rbase + rr;
        float x0 = 0.f, x1 = 0.f, x2 = 0.f;
        if (t > 0) {
            x0 = prev[row];
            const float* lab = labels + ((size_t)row * SEQ + (t - 1)) * IN_DIM;
            x1 = lab[1]; x2 = lab[2];
        }
        float gir = bir  + x0 * wi00 + x1 * wi10 + x2 * wi20;
        float giz = biz  + x0 * wi01 + x1 * wi11 + x2 * wi21;
        float gin = bin_ + x0 * wi02 + x1 * wi12 + x2 * wi22;
        float rg = sigmoidf(gir + ar[rr]);
        float zg = sigmoidf(giz + az[rr]);
        float ng = tanhf(gin + rg * an[rr]);
        float hj = hs[w * 8 + rr][j];
        float hn = (1.0f - zg) * ng + zg * hj;
        h0[(size_t)row * HDIM + j] = hn;
        hs[w * 8 + rr][j] = hn;        // same-wave reads below only
    }

    // repack updated state for proj
    #pragma unroll
    for (int q = 0; q < 4; ++q) {
        int idx = q * 64 + j;
        int r = idx >> 5, k2 = idx & 31;
        float2 v = *(const float2*)&hs[w * 8 + r][k2 * 2];
        hp[w * 8 + r][k2] = pkh2(v.x, v.y);
    }

    // ---- projection via dot2 ----
    float a0[8], a1[8], a2[8], a3[8], a4[8], a5[8];
    #pragma unroll
    for (int rr = 0; rr < 8; ++rr) { a0[rr]=0.f; a1[rr]=0.f; a2[rr]=0.f; a3[rr]=0.f; a4[rr]=0.f; a5[rr]=0.f; }

    for (int k2 = 0; k2 < 32; ++k2) {
        u32 m0 = MH2[k2 * 384 + j];
        u32 m1 = MH2[k2 * 384 + 64 + j];
        u32 m2 = MH2[k2 * 384 + 128 + j];
        u32 m3 = MH2[k2 * 384 + 192 + j];
        u32 m4 = MH2[k2 * 384 + 256 + j];
        u32 m5 = MH2[k2 * 384 + 320 + j];
        #pragma unroll
        for (int rr = 0; rr < 8; ++rr) {
            u32 hh = hp[w * 8 + rr][k2];
            a0[rr] = dot2(m0, hh, a0[rr]);
            a1[rr] = dot2(m1, hh, a1[rr]);
            a2[rr] = dot2(m2, hh, a2[rr]);
            a3[rr] = dot2(m3, hh, a3[rr]);
            a4[rr] = dot2(m4, hh, a4[rr]);
            a5[rr] = dot2(m5, hh, a5[rr]);
        }
    }

    #pragma unroll
    for (int rr = 0; rr < 8; ++rr) {
        size_t row = rbase + rr;
        float stj = hs[w * 8 + rr][j];
        Pd[row * 64 + j] = make_uint2(pack2(a0[rr], a1[rr]), pack2(a2[rr], 0.f));
        u32 pk = __builtin_amdgcn_cvt_pk_fp8_f32(a3[rr], a4[rr], 0u, false);
        pk = __builtin_amdgcn_cvt_pk_fp8_f32(a5[rr], stj, pk, true);
        PsF8[row * 64 + j] = pk;
    }
}

// ---------------------------------------------------------------------------
// FUSED edge aggregation + GRU2 + pred. fp8 Ps reads; fdot2 gru2 loop.
// ---------------------------------------------------------------------------
__global__ __launch_bounds__(256) void edge_gru2_kernel(const int* __restrict__ row_ptr,
                                                        const int* __restrict__ csr_src,
                                                        const float* __restrict__ csr_uv,
                                                        const uint2* __restrict__ Pd,
                                                        const u32* __restrict__ PsF8,
                                                        const u32* __restrict__ W2H2,
                                                        const float* __restrict__ bi2,
                                                        const float* __restrict__ bh2,
                                                        const float* __restrict__ Wo,
                                                        const float* __restrict__ fpred,
                                                        float* __restrict__ h1,
                                                        float* __restrict__ prev,
                                                        float* __restrict__ out,
                                                        int t)
{
    int d = blockIdx.x;
    int tid = threadIdx.x;
    int w = tid >> 6, j = tid & 63;

    __shared__ float red[4][BATCH][HDIM];   // 16 KB
    __shared__ float gs[BATCH][HDIM];       //  4 KB
    __shared__ float hs[BATCH][HDIM];       //  4 KB
    __shared__ u32 gs2[BATCH][32];          //  2 KB
    __shared__ u32 hs2[BATCH][32];          //  2 KB

    // stage h1 rows early: global latency hides under the edge loop
    #pragma unroll
    for (int rr = 0; rr < 4; ++rr)
        hs[w * 4 + rr][j] = h1[(size_t)(d * BATCH + w * 4 + rr) * HDIM + j];

    // ---------------- phase 1: edge aggregation ----------------
    uint2 pdreg[BATCH];
    #pragma unroll
    for (int b = 0; b < BATCH; ++b)
        pdreg[b] = Pd[((size_t)d * BATCH + b) * 64 + j];

    float acc[BATCH];
    #pragma unroll
    for (int b = 0; b < BATCH; ++b) acc[b] = 0.0f;

    int start = row_ptr[d], end = row_ptr[d + 1];
    for (int p = start + w; p < end; p += 4) {
        int s = csr_src[p];
        float u = csr_uv[p * 2], v = csr_uv[p * 2 + 1];

        float al[BATCH], stj[BATCH];
        #pragma unroll
        for (int b = 0; b < BATCH; ++b) {
            uint2 pd = pdreg[b];
            u32 ps = PsF8[((size_t)s * BATCH + b) * 64 + j];
            float c3 = __builtin_amdgcn_cvt_f32_fp8(ps, 0);
            float c4 = __builtin_amdgcn_cvt_f32_fp8(ps, 1);
            float c5 = __builtin_amdgcn_cvt_f32_fp8(ps, 2);
            float st = __builtin_amdgcn_cvt_f32_fp8(ps, 3);
            float a = u * (bf2f(pd.x) + c3)
                    + v * (bf2f(pd.x >> 16) + c4)
                    + bf2f(pd.y) + c5;
            al[b] = (a > 0.0f) ? a : 0.01f * a;
            stj[b] = st;
        }
        float m = al[0];
        #pragma unroll
        for (int b = 1; b < BATCH; ++b) m = fmaxf(m, al[b]);
        float sum = 0.0f;
        #pragma unroll
        for (int b = 0; b < BATCH; ++b) { al[b] = expf(al[b] - m); sum += al[b]; }
        float inv = 1.0f / sum;
        #pragma unroll
        for (int b = 0; b < BATCH; ++b) acc[b] = fmaf(al[b] * inv, stj[b], acc[b]);
    }

    #pragma unroll
    for (int b = 0; b < BATCH; ++b) red[w][b][j] = acc[b];
    __syncthreads();

    // reduce 4 wave-partials -> relu -> gs
    for (int c = tid; c < BATCH * HDIM; c += 256) {
        float s4 = red[0][0][c] + red[1][0][c] + red[2][0][c] + red[3][0][c];
        gs[0][c] = fmaxf(s4, 0.0f);
    }
    __syncthreads();

    // repack gs/hs to f16 pairs (16 rows x 32 pairs each)
    for (int q = tid; q < BATCH * 32; q += 256) {
        int r = q >> 5, k2 = q & 31;
        float2 g2v = *(const float2*)&gs[r][k2 * 2];
        gs2[r][k2] = pkh2(g2v.x, g2v.y);
        float2 h2v = *(const float2*)&hs[r][k2 * 2];
        hs2[r][k2] = pkh2(h2v.x, h2v.y);
    }
    __syncthreads();

    // ---------------- phase 2: gru2 + pred via dot2 (4 rows/wave) ----------------
    float acr[4], acz[4], ain[4], ahn[4];   // r/z merged (i+h), n split
    {
        float b0 = bi2[j] + bh2[j], b1 = bi2[64 + j] + bh2[64 + j];
        float b2 = bi2[128 + j], c2 = bh2[128 + j];
        #pragma unroll
        for (int rr = 0; rr < 4; ++rr) { acr[rr] = b0; acz[rr] = b1; ain[rr] = b2; ahn[rr] = c2; }
    }

    for (int k2 = 0; k2 < 32; ++k2) {
        u32 wir = W2H2[k2 * 384 + j];
        u32 wiz = W2H2[k2 * 384 + 64 + j];
        u32 win = W2H2[k2 * 384 + 128 + j];
        u32 whr = W2H2[k2 * 384 + 192 + j];
        u32 whz = W2H2[k2 * 384 + 256 + j];
        u32 whn = W2H2[k2 * 384 + 320 + j];
        #pragma unroll
        for (int rr = 0; rr < 4; ++rr) {
            u32 gg = gs2[w * 4 + rr][k2];
            u32 hh = hs2[w * 4 + rr][k2];
            acr[rr] = dot2(wir, gg, acr[rr]);  acr[rr] = dot2(whr, hh, acr[rr]);
            acz[rr] = dot2(wiz, gg, acz[rr]);  acz[rr] = dot2(whz, hh, acz[rr]);
            ain[rr] = dot2(win, gg, ain[rr]);  ahn[rr] = dot2(whn, hh, ahn[rr]);
        }
    }

    float woj = Wo[j];
    float fp = fpred[d];
    #pragma unroll
    for (int rr = 0; rr < 4; ++rr) {
        int row = d * BATCH + w * 4 + rr;
        float rg = sigmoidf(acr[rr]);
        float zg = sigmoidf(acz[rr]);
        float ng = tanhf(ain[rr] + rg * ahn[rr]);
        float hj = hs[w * 4 + rr][j];
        float hn = (1.0f - zg) * ng + zg * hj;
        h1[(size_t)row * HDIM + j] = hn;

        float part = hn * woj;
        #pragma unroll
        for (int off = 32; off; off >>= 1) part += __shfl_xor(part, off, 64);
        if (j == rr) {
            float p = part + fp;
            prev[row] = p;
            out[(size_t)row * SEQ + t] = p;   // out[n][b][t][0]
        }
    }
}

// ---------------------------------------------------------------------------
extern "C" void kernel_launch(void* const* d_in, const int* in_sizes, int n_in,
                              void* d_out, int out_size, void* d_ws, size_t ws_size,
                              hipStream_t stream)
{
    const float* hidden0  = (const float*)d_in[0];
    const float* hidden1  = (const float*)d_in[1];
    const float* features = (const float*)d_in[2];
    const float* labels   = (const float*)d_in[3];
    const int*   edge_idx = (const int*)d_in[4];
    const float* Wi1 = (const float*)d_in[5];
    const float* Wh1 = (const float*)d_in[6];
    const float* bi1 = (const float*)d_in[7];
    const float* bh1 = (const float*)d_in[8];
    const float* W1  = (const float*)d_in[9];
    const float* b1  = (const float*)d_in[10];
    const float* W2  = (const float*)d_in[11];
    const float* b2  = (const float*)d_in[12];
    const float* W3  = (const float*)d_in[13];
    const float* b3  = (const float*)d_in[14];
    const float* Wi2 = (const float*)d_in[15];
    const float* Wh2 = (const float*)d_in[16];
    const float* bi2 = (const float*)d_in[17];
    const float* bh2 = (const float*)d_in[18];
    const float* Wo  = (const float*)d_in[19];
    const float* bo  = (const float*)d_in[20];

    float* ws = (float*)d_ws;
    float* h0    = ws;  ws += NB * HDIM;
    float* h1    = ws;  ws += NB * HDIM;
    uint2* Pd    = (uint2*)ws;  ws += NB * HDIM * 2;
    u32*   PsF8  = (u32*)ws;    ws += NB * HDIM;
    float* csr_uv= ws;  ws += EN * 2;
    u32*   WhH2  = (u32*)ws;    ws += 32 * 192;
    u32*   MH2   = (u32*)ws;    ws += 32 * 384;
    u32*   W2H2  = (u32*)ws;    ws += 32 * 384;
    float* Wi1T  = ws;  ws += 3 * 192;
    float* fpred = ws;  ws += N_NODES;
    float* prev  = ws;  ws += NB;
    int*   deg      = (int*)ws;  ws += N_NODES;
    int*   row_ptr  = (int*)ws;  ws += N_NODES + 1;
    int*   row_fill = (int*)ws;  ws += N_NODES;
    int*   csr_src  = (int*)ws;  ws += EN;
    int*   perm     = (int*)ws;  ws += EN;
    float* out   = (float*)d_out;

    prep_kernel<<<256, 256, 0, stream>>>(hidden0, hidden1, features, W3, b3, Wo, bo,
                                         Wh1, Wi1, Wi2, Wh2,
                                         h0, h1, WhH2, MH2, W2H2, Wi1T, fpred, prev);
    deg_init_kernel<<<(N_NODES + 255) / 256, 256, 0, stream>>>(deg);
    deg_count_kernel<<<(E_EDGES + 255) / 256, 256, 0, stream>>>(edge_idx, deg);
    scan_kernel<<<1, 1024, 0, stream>>>(deg, row_ptr, row_fill);
    scatter_kernel<<<(EN + 255) / 256, 256, 0, stream>>>(edge_idx, row_fill, csr_src, perm);
    edge_mlp_kernel<<<(EN + 3) / 4, 256, 0, stream>>>(edge_idx, features, W1, b1, W2, b2,
                                                      perm, csr_uv);

    for (int t = 0; t < SEQ; ++t) {
        gru1_proj_kernel<<<NB / 32, 256, 0, stream>>>(labels, prev, Wi1T, WhH2, bi1, bh1,
                                                      MH2, h0, Pd, PsF8, t);
        edge_gru2_kernel<<<N_NODES, 256, 0, stream>>>(row_ptr, csr_src, csr_uv, Pd, PsF8,
                                                      W2H2, bi2, bh2, Wo, fpred,
                                                      h1, prev, out, t);
    }
}

// Round 15
// 847.775 us; speedup vs baseline: 1.1301x; 1.1301x over previous
//
#include <hip/hip_runtime.h>

#define N_NODES 1000
#define BATCH 16
#define SEQ 12
#define IN_DIM 3
#define HDIM 64
#define E_EDGES 16000
#define EN (E_EDGES + N_NODES)
#define NB (N_NODES * BATCH)

typedef unsigned int u32;
typedef unsigned short u16;
typedef __fp16 h2_t __attribute__((ext_vector_type(2)));

__device__ __forceinline__ float sigmoidf(float x) { return 1.0f / (1.0f + expf(-x)); }

__device__ __forceinline__ u16 f2bf(float x) {
    u32 u = __builtin_bit_cast(u32, x);
    u32 r = (u + 0x7fffu + ((u >> 16) & 1u)) >> 16;
    return (u16)r;
}
__device__ __forceinline__ float bf2f(u32 h) {
    return __builtin_bit_cast(float, (h & 0xffffu) << 16);
}
__device__ __forceinline__ u32 pack2(float a, float b) {
    return (u32)f2bf(a) | ((u32)f2bf(b) << 16);
}

__device__ __forceinline__ u32 pkh2(float a, float b) {
    h2_t h = __builtin_amdgcn_cvt_pkrtz(a, b);
    return __builtin_bit_cast(u32, h);
}
#if __has_builtin(__builtin_amdgcn_fdot2)
__device__ __forceinline__ float dot2(u32 a, u32 b, float c) {
    return __builtin_amdgcn_fdot2(__builtin_bit_cast(h2_t, a),
                                  __builtin_bit_cast(h2_t, b), c, false);
}
#else
__device__ __forceinline__ float dot2(u32 a, u32 b, float c) {
    h2_t x = __builtin_bit_cast(h2_t, a);
    h2_t y = __builtin_bit_cast(h2_t, b);
    return c + (float)x.x * (float)y.x + (float)x.y * (float)y.y;
}
#endif

// ---------------------------------------------------------------------------
// prep: carries, fp32 transposed weights (gru1/proj), f16-pair W2H2 (gru2),
// fpred, zero prev
// ---------------------------------------------------------------------------
__global__ void prep_kernel(const float* __restrict__ hidden0,
                            const float* __restrict__ hidden1,
                            const float* __restrict__ features,
                            const float* __restrict__ W3,
                            const float* __restrict__ b3,
                            const float* __restrict__ Wo,
                            const float* __restrict__ bo,
                            const float* __restrict__ Wh1,
                            const float* __restrict__ Wi1,
                            const float* __restrict__ Wi2,
                            const float* __restrict__ Wh2,
                            float* __restrict__ h0, float* __restrict__ h1,
                            float* __restrict__ M,
                            float* __restrict__ Wh1T, float* __restrict__ Wi1T,
                            u32* __restrict__ W2H2,
                            float* __restrict__ fpred, float* __restrict__ prev)
{
    int tid = blockIdx.x * blockDim.x + threadIdx.x;
    int stride = gridDim.x * blockDim.x;

    for (int i = tid; i < NB * HDIM; i += stride) { h0[i] = hidden0[i]; h1[i] = hidden1[i]; }

    for (int i = tid; i < 64 * 384; i += stride) {
        int k = i / 384, c = i % 384;
        int grp = c / 64, h = c % 64;
        int kk = (grp < 3 ? k : 64 + k) * 64 + h;
        float val;
        if (grp == 0 || grp == 3)      val = W3[kk * 2 + 0];
        else if (grp == 1 || grp == 4) val = W3[kk * 2 + 1];
        else                           val = b3[kk];
        M[i] = val;
    }

    for (int i = tid; i < 192 * 64; i += stride) {
        int k = i / 192, gj = i % 192;
        Wh1T[i] = Wh1[gj * 64 + k];
    }
    for (int i = tid; i < 3 * 192; i += stride) {
        int c = i / 192, gj = i % 192;
        Wi1T[i] = Wi1[gj * 3 + c];
    }

    for (int i = tid; i < 32 * 384; i += stride) {
        int k2 = i / 384, cc = i % 384;
        float v0, v1;
        if (cc < 192) {
            v0 = Wi2[cc * 64 + 2 * k2]; v1 = Wi2[cc * 64 + 2 * k2 + 1];
        } else {
            int gj = cc - 192;
            v0 = Wh2[gj * 64 + 2 * k2]; v1 = Wh2[gj * 64 + 2 * k2 + 1];
        }
        W2H2[i] = pkh2(v0, v1);
    }

    for (int i = tid; i < NB; i += stride) prev[i] = 0.0f;

    for (int n = tid; n < N_NODES; n += stride) {
        float acc = bo[0];
        for (int h = 0; h < HDIM; ++h) acc += features[n * HDIM + h] * Wo[64 + h];
        fpred[n] = acc;
    }
}

// ---------------------------------------------------------------------------
// CSR build (runs once per launch)
// ---------------------------------------------------------------------------
__global__ void deg_init_kernel(int* __restrict__ deg)
{
    int n = blockIdx.x * blockDim.x + threadIdx.x;
    if (n < N_NODES) deg[n] = 1;   // self-loop
}

__global__ void deg_count_kernel(const int* __restrict__ edge_index, int* __restrict__ deg)
{
    int e = blockIdx.x * blockDim.x + threadIdx.x;
    if (e < E_EDGES) atomicAdd(&deg[edge_index[E_EDGES + e]], 1);
}

__global__ __launch_bounds__(1024) void scan_kernel(const int* __restrict__ deg,
                                                    int* __restrict__ row_ptr,
                                                    int* __restrict__ row_fill)
{
    __shared__ int s[1024];
    int tid = threadIdx.x;
    int x = (tid < N_NODES) ? deg[tid] : 0;
    s[tid] = x;
    __syncthreads();
    for (int off = 1; off < 1024; off <<= 1) {
        int v = (tid >= off) ? s[tid - off] : 0;
        __syncthreads();
        s[tid] += v;
        __syncthreads();
    }
    int incl = s[tid];
    int excl = incl - x;
    if (tid < N_NODES) { row_ptr[tid] = excl; row_fill[tid] = excl; }
    if (tid == N_NODES - 1) row_ptr[N_NODES] = incl;
}

__global__ void scatter_kernel(const int* __restrict__ edge_index,
                               int* __restrict__ row_fill,
                               int* __restrict__ csr_src,
                               int* __restrict__ perm)
{
    int e = blockIdx.x * blockDim.x + threadIdx.x;
    if (e < E_EDGES) {
        int s = edge_index[e];
        int d = edge_index[E_EDGES + e];
        int p = atomicAdd(&row_fill[d], 1);
        csr_src[p] = s;
        perm[e] = p;
    } else if (e < EN) {
        int n = e - E_EDGES;
        int p = atomicAdd(&row_fill[n], 1);
        csr_src[p] = n;
        perm[e] = p;
    }
}

// ---------------------------------------------------------------------------
// edge MLP -> u,v written in CSR order via perm (runs once)
// ---------------------------------------------------------------------------
__global__ __launch_bounds__(256) void edge_mlp_kernel(const int* __restrict__ edge_index,
                                                       const float* __restrict__ features,
                                                       const float* __restrict__ W1,
                                                       const float* __restrict__ b1,
                                                       const float* __restrict__ W2,
                                                       const float* __restrict__ b2,
                                                       const int* __restrict__ perm,
                                                       float* __restrict__ csr_uv)
{
    int w = threadIdx.x >> 6, j = threadIdx.x & 63;
    int e = blockIdx.x * 4 + w;
    int s, d;
    if (e < E_EDGES) { s = edge_index[e]; d = edge_index[E_EDGES + e]; }
    else             { s = e - E_EDGES; d = s; }

    __shared__ float ft[4][128];
    __shared__ float w1s[4][16];
    ft[w][j]      = features[d * HDIM + j];   // dst half first
    ft[w][64 + j] = features[s * HDIM + j];
    __syncthreads();

    int o = j & 15, part = j >> 4;
    float acc = 0.0f;
    #pragma unroll 8
    for (int kk = 0; kk < 32; ++kk)
        acc += ft[w][part * 32 + kk] * W1[o * 128 + part * 32 + kk];
    acc += __shfl_xor(acc, 16, 64);
    acc += __shfl_xor(acc, 32, 64);
    if (j < 16) w1s[w][j] = sigmoidf(acc + b1[j]);
    __syncthreads();
    if (j < 2) {
        float a2 = b2[j];
        #pragma unroll
        for (int k = 0; k < 16; ++k) a2 += w1s[w][k] * W2[j * 16 + k];
        csr_uv[perm[e] * 2 + j] = sigmoidf(a2);
    }
}

// ---------------------------------------------------------------------------
// Fused GRU1 + projection (round-12 proven fp32 version).
// 256 threads = 4 waves x 8 rows; LDS broadcast reads; bf16 Pd + fp8 Ps out.
// ---------------------------------------------------------------------------
__global__ __launch_bounds__(256) void gru1_proj_kernel(const float* __restrict__ labels,
                                                        const float* __restrict__ prev,
                                                        const float* __restrict__ Wi1T,
                                                        const float* __restrict__ Wh1T,
                                                        const float* __restrict__ bi1,
                                                        const float* __restrict__ bh1,
                                                        const float* __restrict__ M,
                                                        float* __restrict__ h0,
                                                        uint2* __restrict__ Pd,
                                                        u32* __restrict__ PsF8,
                                                        int t)
{
    int w = threadIdx.x >> 6, j = threadIdx.x & 63;
    int rbase = blockIdx.x * 32 + w * 8;
    __shared__ float hs[32][64];   // each wave owns its 8 rows

    #pragma unroll
    for (int rr = 0; rr < 8; ++rr)
        hs[w * 8 + rr][j] = h0[(size_t)(rbase + rr) * HDIM + j];

    float ar[8], az[8], an[8];
    {
        float br = bh1[j], bz = bh1[64 + j], bn = bh1[128 + j];
        #pragma unroll
        for (int rr = 0; rr < 8; ++rr) { ar[rr] = br; az[rr] = bz; an[rr] = bn; }
    }

    for (int k = 0; k < 64; k += 2) {
        const float* w0 = &Wh1T[(size_t)k * 192 + j];
        float wr0 = w0[0], wz0 = w0[64], wn0 = w0[128];
        float wr1 = w0[192], wz1 = w0[256], wn1 = w0[320];
        #pragma unroll
        for (int rr = 0; rr < 8; ++rr) {
            float2 h2 = *(const float2*)&hs[w * 8 + rr][k];
            ar[rr] = fmaf(wr0, h2.x, ar[rr]);
            az[rr] = fmaf(wz0, h2.x, az[rr]);
            an[rr] = fmaf(wn0, h2.x, an[rr]);
            ar[rr] = fmaf(wr1, h2.y, ar[rr]);
            az[rr] = fmaf(wz1, h2.y, az[rr]);
            an[rr] = fmaf(wn1, h2.y, an[rr]);
        }
    }

    float wi00 = Wi1T[j],       wi01 = Wi1T[64 + j],       wi02 = Wi1T[128 + j];
    float wi10 = Wi1T[192 + j], wi11 = Wi1T[192 + 64 + j], wi12 = Wi1T[192 + 128 + j];
    float wi20 = Wi1T[384 + j], wi21 = Wi1T[384 + 64 + j], wi22 = Wi1T[384 + 128 + j];
    float bir = bi1[j], biz = bi1[64 + j], bin_ = bi1[128 + j];

    #pragma unroll
    for (int rr = 0; rr < 8; ++rr) {
        int row = rbase + rr;
        float x0 = 0.f, x1 = 0.f, x2 = 0.f;
        if (t > 0) {
            x0 = prev[row];
            const float* lab = labels + ((size_t)row * SEQ + (t - 1)) * IN_DIM;
            x1 = lab[1]; x2 = lab[2];
        }
        float gir = bir  + x0 * wi00 + x1 * wi10 + x2 * wi20;
        float giz = biz  + x0 * wi01 + x1 * wi11 + x2 * wi21;
        float gin = bin_ + x0 * wi02 + x1 * wi12 + x2 * wi22;
        float rg = sigmoidf(gir + ar[rr]);
        float zg = sigmoidf(giz + az[rr]);
        float ng = tanhf(gin + rg * an[rr]);
        float hj = hs[w * 8 + rr][j];
        float hn = (1.0f - zg) * ng + zg * hj;
        h0[(size_t)row * HDIM + j] = hn;
        hs[w * 8 + rr][j] = hn;        // same wave reads below; in-order LDS
    }

    float a0[8], a1[8], a2[8], a3[8], a4[8], a5[8];
    #pragma unroll
    for (int rr = 0; rr < 8; ++rr) { a0[rr]=0.f; a1[rr]=0.f; a2[rr]=0.f; a3[rr]=0.f; a4[rr]=0.f; a5[rr]=0.f; }

    for (int k = 0; k < 64; ++k) {
        const float* mrow = &M[(size_t)k * 384 + j];
        float m0 = mrow[0],   m1 = mrow[64],  m2 = mrow[128];
        float m3 = mrow[192], m4 = mrow[256], m5 = mrow[320];
        #pragma unroll
        for (int rr = 0; rr < 8; ++rr) {
            float hk = hs[w * 8 + rr][k];
            a0[rr] = fmaf(m0, hk, a0[rr]); a1[rr] = fmaf(m1, hk, a1[rr]);
            a2[rr] = fmaf(m2, hk, a2[rr]); a3[rr] = fmaf(m3, hk, a3[rr]);
            a4[rr] = fmaf(m4, hk, a4[rr]); a5[rr] = fmaf(m5, hk, a5[rr]);
        }
    }

    #pragma unroll
    for (int rr = 0; rr < 8; ++rr) {
        size_t row = rbase + rr;
        float stj = hs[w * 8 + rr][j];
        Pd[row * 64 + j] = make_uint2(pack2(a0[rr], a1[rr]), pack2(a2[rr], 0.f));
        u32 pk = __builtin_amdgcn_cvt_pk_fp8_f32(a3[rr], a4[rr], 0u, false);
        pk = __builtin_amdgcn_cvt_pk_fp8_f32(a5[rr], stj, pk, true);
        PsF8[row * 64 + j] = pk;
    }
}

// ---------------------------------------------------------------------------
// FUSED edge aggregation + GRU2 + pred (round-14 dot2 version, kept).
// fp8 Ps reads; f16-pair W2H2 gru2 loop.
// ---------------------------------------------------------------------------
__global__ __launch_bounds__(256) void edge_gru2_kernel(const int* __restrict__ row_ptr,
                                                        const int* __restrict__ csr_src,
                                                        const float* __restrict__ csr_uv,
                                                        const uint2* __restrict__ Pd,
                                                        const u32* __restrict__ PsF8,
                                                        const u32* __restrict__ W2H2,
                                                        const float* __restrict__ bi2,
                                                        const float* __restrict__ bh2,
                                                        const float* __restrict__ Wo,
                                                        const float* __restrict__ fpred,
                                                        float* __restrict__ h1,
                                                        float* __restrict__ prev,
                                                        float* __restrict__ out,
                                                        int t)
{
    int d = blockIdx.x;
    int tid = threadIdx.x;
    int w = tid >> 6, j = tid & 63;

    __shared__ float red[4][BATCH][HDIM];   // 16 KB
    __shared__ float gs[BATCH][HDIM];       //  4 KB
    __shared__ float hs[BATCH][HDIM];       //  4 KB
    __shared__ u32 gs2[BATCH][32];          //  2 KB
    __shared__ u32 hs2[BATCH][32];          //  2 KB

    // stage h1 rows early: global latency hides under the edge loop
    #pragma unroll
    for (int rr = 0; rr < 4; ++rr)
        hs[w * 4 + rr][j] = h1[(size_t)(d * BATCH + w * 4 + rr) * HDIM + j];

    // ---------------- phase 1: edge aggregation ----------------
    uint2 pdreg[BATCH];
    #pragma unroll
    for (int b = 0; b < BATCH; ++b)
        pdreg[b] = Pd[((size_t)d * BATCH + b) * 64 + j];

    float acc[BATCH];
    #pragma unroll
    for (int b = 0; b < BATCH; ++b) acc[b] = 0.0f;

    int start = row_ptr[d], end = row_ptr[d + 1];
    for (int p = start + w; p < end; p += 4) {
        int s = csr_src[p];
        float u = csr_uv[p * 2], v = csr_uv[p * 2 + 1];

        float al[BATCH], stj[BATCH];
        #pragma unroll
        for (int b = 0; b < BATCH; ++b) {
            uint2 pd = pdreg[b];
            u32 ps = PsF8[((size_t)s * BATCH + b) * 64 + j];
            float c3 = __builtin_amdgcn_cvt_f32_fp8(ps, 0);
            float c4 = __builtin_amdgcn_cvt_f32_fp8(ps, 1);
            float c5 = __builtin_amdgcn_cvt_f32_fp8(ps, 2);
            float st = __builtin_amdgcn_cvt_f32_fp8(ps, 3);
            float a = u * (bf2f(pd.x) + c3)
                    + v * (bf2f(pd.x >> 16) + c4)
                    + bf2f(pd.y) + c5;
            al[b] = (a > 0.0f) ? a : 0.01f * a;
            stj[b] = st;
        }
        float m = al[0];
        #pragma unroll
        for (int b = 1; b < BATCH; ++b) m = fmaxf(m, al[b]);
        float sum = 0.0f;
        #pragma unroll
        for (int b = 0; b < BATCH; ++b) { al[b] = expf(al[b] - m); sum += al[b]; }
        float inv = 1.0f / sum;
        #pragma unroll
        for (int b = 0; b < BATCH; ++b) acc[b] = fmaf(al[b] * inv, stj[b], acc[b]);
    }

    #pragma unroll
    for (int b = 0; b < BATCH; ++b) red[w][b][j] = acc[b];
    __syncthreads();

    // reduce 4 wave-partials -> relu -> gs
    for (int c = tid; c < BATCH * HDIM; c += 256) {
        float s4 = red[0][0][c] + red[1][0][c] + red[2][0][c] + red[3][0][c];
        gs[0][c] = fmaxf(s4, 0.0f);
    }
    __syncthreads();

    // repack gs/hs to f16 pairs
    for (int q = tid; q < BATCH * 32; q += 256) {
        int r = q >> 5, k2 = q & 31;
        float2 g2v = *(const float2*)&gs[r][k2 * 2];
        gs2[r][k2] = pkh2(g2v.x, g2v.y);
        float2 h2v = *(const float2*)&hs[r][k2 * 2];
        hs2[r][k2] = pkh2(h2v.x, h2v.y);
    }
    __syncthreads();

    // ---------------- phase 2: gru2 + pred via dot2 (4 rows/wave) ----------------
    float acr[4], acz[4], ain[4], ahn[4];
    {
        float b0 = bi2[j] + bh2[j], b1 = bi2[64 + j] + bh2[64 + j];
        float b2 = bi2[128 + j], c2 = bh2[128 + j];
        #pragma unroll
        for (int rr = 0; rr < 4; ++rr) { acr[rr] = b0; acz[rr] = b1; ain[rr] = b2; ahn[rr] = c2; }
    }

    for (int k2 = 0; k2 < 32; ++k2) {
        u32 wir = W2H2[k2 * 384 + j];
        u32 wiz = W2H2[k2 * 384 + 64 + j];
        u32 win = W2H2[k2 * 384 + 128 + j];
        u32 whr = W2H2[k2 * 384 + 192 + j];
        u32 whz = W2H2[k2 * 384 + 256 + j];
        u32 whn = W2H2[k2 * 384 + 320 + j];
        #pragma unroll
        for (int rr = 0; rr < 4; ++rr) {
            u32 gg = gs2[w * 4 + rr][k2];
            u32 hh = hs2[w * 4 + rr][k2];
            acr[rr] = dot2(wir, gg, acr[rr]);  acr[rr] = dot2(whr, hh, acr[rr]);
            acz[rr] = dot2(wiz, gg, acz[rr]);  acz[rr] = dot2(whz, hh, acz[rr]);
            ain[rr] = dot2(win, gg, ain[rr]);  ahn[rr] = dot2(whn, hh, ahn[rr]);
        }
    }

    float woj = Wo[j];
    float fp = fpred[d];
    #pragma unroll
    for (int rr = 0; rr < 4; ++rr) {
        int row = d * BATCH + w * 4 + rr;
        float rg = sigmoidf(acr[rr]);
        float zg = sigmoidf(acz[rr]);
        float ng = tanhf(ain[rr] + rg * ahn[rr]);
        float hj = hs[w * 4 + rr][j];
        float hn = (1.0f - zg) * ng + zg * hj;
        h1[(size_t)row * HDIM + j] = hn;

        float part = hn * woj;
        #pragma unroll
        for (int off = 32; off; off >>= 1) part += __shfl_xor(part, off, 64);
        if (j == rr) {
            float p = part + fp;
            prev[row] = p;
            out[(size_t)row * SEQ + t] = p;   // out[n][b][t][0]
        }
    }
}

// ---------------------------------------------------------------------------
extern "C" void kernel_launch(void* const* d_in, const int* in_sizes, int n_in,
                              void* d_out, int out_size, void* d_ws, size_t ws_size,
                              hipStream_t stream)
{
    const float* hidden0  = (const float*)d_in[0];
    const float* hidden1  = (const float*)d_in[1];
    const float* features = (const float*)d_in[2];
    const float* labels   = (const float*)d_in[3];
    const int*   edge_idx = (const int*)d_in[4];
    const float* Wi1 = (const float*)d_in[5];
    const float* Wh1 = (const float*)d_in[6];
    const float* bi1 = (const float*)d_in[7];
    const float* bh1 = (const float*)d_in[8];
    const float* W1  = (const float*)d_in[9];
    const float* b1  = (const float*)d_in[10];
    const float* W2  = (const float*)d_in[11];
    const float* b2  = (const float*)d_in[12];
    const float* W3  = (const float*)d_in[13];
    const float* b3  = (const float*)d_in[14];
    const float* Wi2 = (const float*)d_in[15];
    const float* Wh2 = (const float*)d_in[16];
    const float* bi2 = (const float*)d_in[17];
    const float* bh2 = (const float*)d_in[18];
    const float* Wo  = (const float*)d_in[19];
    const float* bo  = (const float*)d_in[20];

    float* ws = (float*)d_ws;
    float* h0    = ws;  ws += NB * HDIM;
    float* h1    = ws;  ws += NB * HDIM;
    uint2* Pd    = (uint2*)ws;  ws += NB * HDIM * 2;
    u32*   PsF8  = (u32*)ws;    ws += NB * HDIM;
    float* csr_uv= ws;  ws += EN * 2;
    float* M     = ws;  ws += 64 * 384;
    float* Wh1T  = ws;  ws += 64 * 192;
    float* Wi1T  = ws;  ws += 3 * 192;
    u32*   W2H2  = (u32*)ws;    ws += 32 * 384;
    float* fpred = ws;  ws += N_NODES;
    float* prev  = ws;  ws += NB;
    int*   deg      = (int*)ws;  ws += N_NODES;
    int*   row_ptr  = (int*)ws;  ws += N_NODES + 1;
    int*   row_fill = (int*)ws;  ws += N_NODES;
    int*   csr_src  = (int*)ws;  ws += EN;
    int*   perm     = (int*)ws;  ws += EN;
    float* out   = (float*)d_out;

    prep_kernel<<<256, 256, 0, stream>>>(hidden0, hidden1, features, W3, b3, Wo, bo,
                                         Wh1, Wi1, Wi2, Wh2,
                                         h0, h1, M, Wh1T, Wi1T, W2H2, fpred, prev);
    deg_init_kernel<<<(N_NODES + 255) / 256, 256, 0, stream>>>(deg);
    deg_count_kernel<<<(E_EDGES + 255) / 256, 256, 0, stream>>>(edge_idx, deg);
    scan_kernel<<<1, 1024, 0, stream>>>(deg, row_ptr, row_fill);
    scatter_kernel<<<(EN + 255) / 256, 256, 0, stream>>>(edge_idx, row_fill, csr_src, perm);
    edge_mlp_kernel<<<(EN + 3) / 4, 256, 0, stream>>>(edge_idx, features, W1, b1, W2, b2,
                                                      perm, csr_uv);

    for (int t = 0; t < SEQ; ++t) {
        gru1_proj_kernel<<<NB / 32, 256, 0, stream>>>(labels, prev, Wi1T, Wh1T, bi1, bh1,
                                                      M, h0, Pd, PsF8, t);
        edge_gru2_kernel<<<N_NODES, 256, 0, stream>>>(row_ptr, csr_src, csr_uv, Pd, PsF8,
                                                      W2H2, bi2, bh2, Wo, fpred,
                                                      h1, prev, out, t);
    }
}